// Round 2
// baseline (359.082 us; speedup 1.0000x reference)
//
#include <hip/hip_runtime.h>

#define NN 50000
#define NE 800000
#define DIN 256
#define F1 96
#define F2 48
#define F3 24
#define EPSL 1e-5f
#define NB 196  // ceil(NN/256)

// ---------------- edge-index access (int32 or int64 storage) ----------------
__device__ __forceinline__ int ld_src(const int* __restrict__ ei, int is64, int e) {
    return is64 ? ei[2 * e] : ei[e];
}
__device__ __forceinline__ int ld_dst(const int* __restrict__ ei, int is64, int e) {
    return is64 ? ei[2 * NE + 2 * e] : ei[NE + e];
}

__global__ void k_detect(const int* __restrict__ ei, int* __restrict__ flag) {
    if (threadIdx.x == 0 && blockIdx.x == 0) {
        int zeros = 0;
        for (int i = 0; i < 64; i++)
            if (ei[2 * i + 1] == 0) zeros++;
        *flag = (zeros >= 60) ? 1 : 0;  // int64: odd int32 words are high halves == 0
    }
}

// ---------------- degree histogram ----------------
__global__ void k_hist(const int* __restrict__ ei, const int* __restrict__ flag,
                       int* __restrict__ cnt) {
    int e = blockIdx.x * blockDim.x + threadIdx.x;
    if (e < NE) {
        int is64 = *flag;
        atomicAdd(&cnt[ld_dst(ei, is64, e)], 1);
    }
}

__global__ void k_dis(const int* __restrict__ cnt, float* __restrict__ dis) {
    int n = blockIdx.x * blockDim.x + threadIdx.x;
    if (n < NN) dis[n] = rsqrtf((float)cnt[n] + 1.0f);
}

// ---------------- scan (exclusive prefix over cnt -> rowstart) ----------------
__global__ void k_scan_reduce(const int* __restrict__ cnt, int* __restrict__ bsum) {
    __shared__ int s[256];
    int t = threadIdx.x;
    int i = blockIdx.x * 256 + t;
    s[t] = (i < NN) ? cnt[i] : 0;
    __syncthreads();
    for (int off = 128; off > 0; off >>= 1) {
        if (t < off) s[t] += s[t + off];
        __syncthreads();
    }
    if (t == 0) bsum[blockIdx.x] = s[0];
}

__global__ void k_scan_top(const int* __restrict__ bsum, int* __restrict__ bsumex,
                           int* __restrict__ rowstart) {
    __shared__ int s[256];
    int t = threadIdx.x;
    int v = (t < NB) ? bsum[t] : 0;
    s[t] = v;
    __syncthreads();
    for (int off = 1; off < 256; off <<= 1) {
        int x = (t >= off) ? s[t - off] : 0;
        __syncthreads();
        s[t] += x;
        __syncthreads();
    }
    if (t < NB) bsumex[t] = s[t] - v;
    if (t == NB - 1) rowstart[NN] = s[t];
}

__global__ void k_scan_fin(const int* __restrict__ cnt, const int* __restrict__ bsumex,
                           int* __restrict__ rowstart) {
    __shared__ int s[256];
    int t = threadIdx.x;
    int i = blockIdx.x * 256 + t;
    int v = (i < NN) ? cnt[i] : 0;
    s[t] = v;
    __syncthreads();
    for (int off = 1; off < 256; off <<= 1) {
        int x = (t >= off) ? s[t - off] : 0;
        __syncthreads();
        s[t] += x;
        __syncthreads();
    }
    if (i < NN) rowstart[i] = bsumex[blockIdx.x] + s[t] - v;
}

// ---------------- CSR fill: csr[i] = {src, weight} ----------------
__global__ void k_fill(const int* __restrict__ ei, const int* __restrict__ flag,
                       const float* __restrict__ dis, const int* __restrict__ rowstart,
                       int* __restrict__ cursor, int2* __restrict__ csr) {
    int e = blockIdx.x * blockDim.x + threadIdx.x;
    if (e < NE) {
        int is64 = *flag;
        int d = ld_dst(ei, is64, e);
        int s = ld_src(ei, is64, e);
        int pos = atomicAdd(&cursor[d], 1);
        float w = dis[s] * dis[d];
        csr[rowstart[d] + pos] = make_int2(s, __float_as_int(w));
    }
}

// ---------------- LayerNorm row stats (one wave per row) ----------------
__global__ void k_lnstats(const float* __restrict__ x, float* __restrict__ mu,
                          float* __restrict__ rstd) {
    int wid = (blockIdx.x * blockDim.x + threadIdx.x) >> 6;
    int lane = threadIdx.x & 63;
    if (wid >= NN) return;
    const float4* xr = (const float4*)(x + (size_t)wid * DIN);
    float4 v = xr[lane];
    float s = v.x + v.y + v.z + v.w;
    float q = v.x * v.x + v.y * v.y + v.z * v.z + v.w * v.w;
    for (int off = 32; off > 0; off >>= 1) {
        s += __shfl_xor(s, off);
        q += __shfl_xor(q, off);
    }
    if (lane == 0) {
        float m = s * (1.f / 256.f);
        float var = q * (1.f / 256.f) - m * m;
        mu[wid] = m;
        rstd[wid] = rsqrtf(var + EPSL);
    }
}

// ---------------- BN constants prep (fold conv bias into BN affine) ----------------
__global__ void k_bnprep(const float* __restrict__ b1, const float* __restrict__ g1,
                         const float* __restrict__ bb1, const float* __restrict__ m1,
                         const float* __restrict__ v1, const float* __restrict__ b2,
                         const float* __restrict__ g2, const float* __restrict__ bb2,
                         const float* __restrict__ m2, const float* __restrict__ v2,
                         const float* __restrict__ b3, const float* __restrict__ g3,
                         const float* __restrict__ bb3, const float* __restrict__ m3,
                         const float* __restrict__ v3, float* __restrict__ sc,
                         float* __restrict__ sh) {
    int t = threadIdx.x;
    if (t < F1) {
        float s = g1[t] * rsqrtf(v1[t] + EPSL);
        sc[t] = s;
        sh[t] = bb1[t] - m1[t] * s + b1[t] * s;
    } else if (t < F1 + F2) {
        int f = t - F1;
        float s = g2[f] * rsqrtf(v2[f] + EPSL);
        sc[t] = s;
        sh[t] = bb2[f] - m2[f] * s + b2[f] * s;
    } else if (t < F1 + F2 + F3) {
        int f = t - F1 - F2;
        float s = g3[f] * rsqrtf(v3[f] + EPSL);
        sc[t] = s;
        sh[t] = bb3[f] - m3[f] * s + b3[f] * s;
    }
}

// ---------------- GEMM1: LN(x) @ W1  (M=NN, K=256, N=96) ----------------
#define G1_BM 64
#define G1_BK 64
#define G1_LDA 68
__global__ __launch_bounds__(256) void k_gemm1(
    const float* __restrict__ x, const float* __restrict__ mu, const float* __restrict__ rstd,
    const float* __restrict__ ln_g, const float* __restrict__ ln_b,
    const float* __restrict__ W1, float* __restrict__ out) {
    __shared__ float At[G1_BK][G1_LDA];  // [k][row]
    __shared__ float Bs[G1_BK][F1];
    int tid = threadIdx.x;
    int brow = blockIdx.x * G1_BM;
    int rg = tid >> 4;  // 0..15 -> rows rg*4..+3
    int cg = tid & 15;  // 0..15 -> cols cg*6..+5
    float acc[4][6] = {};
    for (int k0 = 0; k0 < DIN; k0 += G1_BK) {
#pragma unroll
        for (int i = 0; i < 16; i++) {
            int idx = tid + i * 256;
            int r = idx >> 6;
            int kk = idx & 63;
            int row = brow + r;
            float a = 0.f;
            if (row < NN) {
                float xv = x[(size_t)row * DIN + k0 + kk];
                a = (xv - mu[row]) * rstd[row] * ln_g[k0 + kk] + ln_b[k0 + kk];
            }
            At[kk][r] = a;
        }
#pragma unroll
        for (int i = 0; i < 24; i++) {
            int idx = tid + i * 256;
            int kk = idx / F1;
            int c = idx % F1;
            Bs[kk][c] = W1[(size_t)(k0 + kk) * F1 + c];
        }
        __syncthreads();
#pragma unroll 4
        for (int k = 0; k < G1_BK; k++) {
            float4 a = *(const float4*)&At[k][rg * 4];
            float b[6];
            *(float2*)&b[0] = *(const float2*)&Bs[k][cg * 6];
            *(float2*)&b[2] = *(const float2*)&Bs[k][cg * 6 + 2];
            *(float2*)&b[4] = *(const float2*)&Bs[k][cg * 6 + 4];
#pragma unroll
            for (int j = 0; j < 6; j++) {
                acc[0][j] += a.x * b[j];
                acc[1][j] += a.y * b[j];
                acc[2][j] += a.z * b[j];
                acc[3][j] += a.w * b[j];
            }
        }
        __syncthreads();
    }
#pragma unroll
    for (int i = 0; i < 4; i++) {
        int row = brow + rg * 4 + i;
        if (row < NN) {
            float* o = out + (size_t)row * F1 + cg * 6;
#pragma unroll
            for (int j = 0; j < 6; j++) o[j] = acc[i][j];
        }
    }
}

// ---------------- GEMM2: h[NN,96] @ W2[96,48]  (BM=64, LDS < 64KB) ----------------
__global__ __launch_bounds__(256) void k_gemm2(const float* __restrict__ A,
                                               const float* __restrict__ W,
                                               float* __restrict__ out) {
    __shared__ float At[F1][68];  // [k][row], 96 x 68
    __shared__ float Ws[F1][F2];
    int tid = threadIdx.x;
    int brow = blockIdx.x * 64;
#pragma unroll
    for (int i = 0; i < 24; i++) {
        int idx = tid + i * 256;  // < 6144 = 96*64
        int r = idx / F1;         // 0..63
        int kk = idx % F1;
        int row = brow + r;
        At[kk][r] = (row < NN) ? A[(size_t)row * F1 + kk] : 0.f;
    }
#pragma unroll
    for (int i = 0; i < 18; i++) {
        int idx = tid + i * 256;
        Ws[idx / F2][idx % F2] = W[idx];
    }
    __syncthreads();
    int rg = tid >> 4;  // 0..15 -> rows rg*4
    int cg = tid & 15;  // 0..15 -> cols cg*3
    float acc[4][3] = {};
#pragma unroll 4
    for (int k = 0; k < F1; k++) {
        float4 a = *(const float4*)&At[k][rg * 4];
        float b[3];
        b[0] = Ws[k][cg * 3];
        b[1] = Ws[k][cg * 3 + 1];
        b[2] = Ws[k][cg * 3 + 2];
#pragma unroll
        for (int j = 0; j < 3; j++) {
            acc[0][j] += a.x * b[j];
            acc[1][j] += a.y * b[j];
            acc[2][j] += a.z * b[j];
            acc[3][j] += a.w * b[j];
        }
    }
#pragma unroll
    for (int i = 0; i < 4; i++) {
        int row = brow + rg * 4 + i;
        if (row < NN) {
            float* o = out + (size_t)row * F2 + cg * 3;
#pragma unroll
            for (int j = 0; j < 3; j++) o[j] = acc[i][j];
        }
    }
}

// ---------------- GEMM3: h[NN,48] @ W3[48,24] ----------------
__global__ __launch_bounds__(256) void k_gemm3(const float* __restrict__ A,
                                               const float* __restrict__ W,
                                               float* __restrict__ out) {
    __shared__ float At[F2][132];  // 48 x 132 (BM=128)
    __shared__ float Ws[F2][F3];
    int tid = threadIdx.x;
    int brow = blockIdx.x * 128;
#pragma unroll
    for (int i = 0; i < 24; i++) {
        int idx = tid + i * 256;  // < 6144 = 48*128
        int r = idx / F2;
        int kk = idx % F2;
        int row = brow + r;
        At[kk][r] = (row < NN) ? A[(size_t)row * F2 + kk] : 0.f;
    }
#pragma unroll
    for (int i = 0; i < 5; i++) {
        int idx = tid + i * 256;
        if (idx < F2 * F3) Ws[idx / F3][idx % F3] = W[idx];
    }
    __syncthreads();
    int rg = tid >> 3;  // rows rg*4 (0..31)
    int cg = tid & 7;   // cols cg*3 (0..7)
    float acc[4][3] = {};
#pragma unroll 4
    for (int k = 0; k < F2; k++) {
        float4 a = *(const float4*)&At[k][rg * 4];
        float b[3];
        b[0] = Ws[k][cg * 3];
        b[1] = Ws[k][cg * 3 + 1];
        b[2] = Ws[k][cg * 3 + 2];
#pragma unroll
        for (int j = 0; j < 3; j++) {
            acc[0][j] += a.x * b[j];
            acc[1][j] += a.y * b[j];
            acc[2][j] += a.z * b[j];
            acc[3][j] += a.w * b[j];
        }
    }
#pragma unroll
    for (int i = 0; i < 4; i++) {
        int row = brow + rg * 4 + i;
        if (row < NN) {
            float* o = out + (size_t)row * F3 + cg * 3;
#pragma unroll
            for (int j = 0; j < 3; j++) o[j] = acc[i][j];
        }
    }
}

// ---------------- CSR gather aggregation + self loop + BN + ReLU ----------------
template <int F4>
__global__ __launch_bounds__(256) void k_agg(const float4* __restrict__ hin,
                                             const int2* __restrict__ csr,
                                             const int* __restrict__ rowstart,
                                             const float* __restrict__ dis,
                                             const float* __restrict__ bnsc,
                                             const float* __restrict__ bnsh,
                                             float4* __restrict__ hout) {
    int t = blockIdx.x * blockDim.x + threadIdx.x;
    if (t >= NN * F4) return;
    int n = t / F4;
    int q = t - n * F4;
    int e0 = rowstart[n], e1 = rowstart[n + 1];
    float4 acc = make_float4(0.f, 0.f, 0.f, 0.f);
    for (int e = e0; e < e1; e++) {
        int2 p = csr[e];
        float w = __int_as_float(p.y);
        float4 hv = hin[(size_t)p.x * F4 + q];
        acc.x += hv.x * w;
        acc.y += hv.y * w;
        acc.z += hv.z * w;
        acc.w += hv.w * w;
    }
    float d = dis[n];
    float d2 = d * d;
    float4 hs = hin[(size_t)n * F4 + q];
    acc.x += hs.x * d2;
    acc.y += hs.y * d2;
    acc.z += hs.z * d2;
    acc.w += hs.w * d2;
    const float4 sc = *(const float4*)&bnsc[q * 4];
    const float4 sh = *(const float4*)&bnsh[q * 4];
    float4 o;
    o.x = fmaxf(acc.x * sc.x + sh.x, 0.f);
    o.y = fmaxf(acc.y * sc.y + sh.y, 0.f);
    o.z = fmaxf(acc.z * sc.z + sh.z, 0.f);
    o.w = fmaxf(acc.w * sc.w + sh.w, 0.f);
    hout[t] = o;
}

// ---------------- classifier: fc1 + LN + relu + fc2 ----------------
__global__ __launch_bounds__(256) void k_cls(const float* __restrict__ h,
                                             const float* __restrict__ fc1W,
                                             const float* __restrict__ fc1b,
                                             const float* __restrict__ lng,
                                             const float* __restrict__ lnb,
                                             const float* __restrict__ fc2W,
                                             const float* __restrict__ fc2b,
                                             float* __restrict__ out) {
    __shared__ float sW1[24 * 12], sW2[12 * 8], sb1[12], sg[12], sb[12], sb2[8];
    int tid = threadIdx.x;
    for (int i = tid; i < 288; i += 256) sW1[i] = fc1W[i];  // FIX: cover all 288
    if (tid < 96) sW2[tid] = fc2W[tid];
    if (tid < 12) {
        sb1[tid] = fc1b[tid];
        sg[tid] = lng[tid];
        sb[tid] = lnb[tid];
    }
    if (tid < 8) sb2[tid] = fc2b[tid];
    __syncthreads();
    int n = blockIdx.x * blockDim.x + tid;
    if (n >= NN) return;
    float hv[24];
    const float4* hp = (const float4*)(h + (size_t)n * 24);
#pragma unroll
    for (int i = 0; i < 6; i++) {
        float4 v = hp[i];
        hv[i * 4] = v.x;
        hv[i * 4 + 1] = v.y;
        hv[i * 4 + 2] = v.z;
        hv[i * 4 + 3] = v.w;
    }
    float z[12];
#pragma unroll
    for (int j = 0; j < 12; j++) {
        float a = sb1[j];
#pragma unroll
        for (int k = 0; k < 24; k++) a += hv[k] * sW1[k * 12 + j];
        z[j] = a;
    }
    float s = 0.f, q = 0.f;
#pragma unroll
    for (int j = 0; j < 12; j++) {
        s += z[j];
        q += z[j] * z[j];
    }
    float m = s * (1.f / 12.f);
    float var = q * (1.f / 12.f) - m * m;
    float rs = rsqrtf(var + EPSL);
#pragma unroll
    for (int j = 0; j < 12; j++) z[j] = fmaxf((z[j] - m) * rs * sg[j] + sb[j], 0.f);
    float o[8];
#pragma unroll
    for (int c = 0; c < 8; c++) {
        float a = sb2[c];
#pragma unroll
        for (int j = 0; j < 12; j++) a += z[j] * sW2[j * 8 + c];
        o[c] = a;
    }
    float4* op = (float4*)(out + (size_t)n * 8);
    op[0] = make_float4(o[0], o[1], o[2], o[3]);
    op[1] = make_float4(o[4], o[5], o[6], o[7]);
}

// ---------------- launch ----------------
extern "C" void kernel_launch(void* const* d_in, const int* in_sizes, int n_in,
                              void* d_out, int out_size, void* d_ws, size_t ws_size,
                              hipStream_t stream) {
    const float* x = (const float*)d_in[0];
    const int* ei = (const int*)d_in[1];
    const float* ln_g = (const float*)d_in[2];
    const float* ln_b = (const float*)d_in[3];
    const float* W1 = (const float*)d_in[4];
    const float* b1 = (const float*)d_in[5];
    const float* bn1_g = (const float*)d_in[6];
    const float* bn1_b = (const float*)d_in[7];
    const float* bn1_m = (const float*)d_in[8];
    const float* bn1_v = (const float*)d_in[9];
    const float* W2 = (const float*)d_in[10];
    const float* b2 = (const float*)d_in[11];
    const float* bn2_g = (const float*)d_in[12];
    const float* bn2_b = (const float*)d_in[13];
    const float* bn2_m = (const float*)d_in[14];
    const float* bn2_v = (const float*)d_in[15];
    const float* W3 = (const float*)d_in[16];
    const float* b3 = (const float*)d_in[17];
    const float* bn3_g = (const float*)d_in[18];
    const float* bn3_b = (const float*)d_in[19];
    const float* bn3_m = (const float*)d_in[20];
    const float* bn3_v = (const float*)d_in[21];
    const float* fc1_W = (const float*)d_in[22];
    const float* fc1_b = (const float*)d_in[23];
    const float* lnc_g = (const float*)d_in[24];
    const float* lnc_b = (const float*)d_in[25];
    const float* fc2_W = (const float*)d_in[26];
    const float* fc2_b = (const float*)d_in[27];

    char* w = (char*)d_ws;
    auto alloc = [&](size_t bytes) {
        char* p = w;
        w += (bytes + 255) & ~(size_t)255;
        return p;
    };
    int* flag = (int*)alloc(4);
    int* cnt = (int*)alloc(NN * 4);
    int* cursor = (int*)alloc(NN * 4);
    int* bsum = (int*)alloc(1024);
    int* bsumex = (int*)alloc(1024);
    int* rowstart = (int*)alloc((NN + 1) * 4);
    float* dis = (float*)alloc(NN * 4);
    float* mu = (float*)alloc(NN * 4);
    float* rstd = (float*)alloc(NN * 4);
    float* bnsc = (float*)alloc(1024);
    float* bnsh = (float*)alloc(1024);
    int2* csr = (int2*)alloc((size_t)NE * 8);
    float* bufA = (float*)alloc((size_t)NN * F1 * 4);
    float* bufB = (float*)alloc((size_t)NN * F1 * 4);

    hipMemsetAsync(cnt, 0, NN * 4, stream);
    hipMemsetAsync(cursor, 0, NN * 4, stream);
    k_detect<<<1, 64, 0, stream>>>(ei, flag);
    k_hist<<<(NE + 255) / 256, 256, 0, stream>>>(ei, flag, cnt);
    k_dis<<<(NN + 255) / 256, 256, 0, stream>>>(cnt, dis);
    k_scan_reduce<<<NB, 256, 0, stream>>>(cnt, bsum);
    k_scan_top<<<1, 256, 0, stream>>>(bsum, bsumex, rowstart);
    k_scan_fin<<<NB, 256, 0, stream>>>(cnt, bsumex, rowstart);
    k_fill<<<(NE + 255) / 256, 256, 0, stream>>>(ei, flag, dis, rowstart, cursor, csr);
    k_lnstats<<<(NN * 64) / 256, 256, 0, stream>>>(x, mu, rstd);
    k_bnprep<<<1, 256, 0, stream>>>(b1, bn1_g, bn1_b, bn1_m, bn1_v, b2, bn2_g, bn2_b,
                                    bn2_m, bn2_v, b3, bn3_g, bn3_b, bn3_m, bn3_v, bnsc,
                                    bnsh);
    k_gemm1<<<(NN + G1_BM - 1) / G1_BM, 256, 0, stream>>>(x, mu, rstd, ln_g, ln_b, W1,
                                                          bufA);
    k_agg<24><<<(NN * 24 + 255) / 256, 256, 0, stream>>>(
        (const float4*)bufA, csr, rowstart, dis, bnsc, bnsh, (float4*)bufB);
    k_gemm2<<<(NN + 63) / 64, 256, 0, stream>>>(bufB, W2, bufA);
    k_agg<12><<<(NN * 12 + 255) / 256, 256, 0, stream>>>(
        (const float4*)bufA, csr, rowstart, dis, bnsc + F1, bnsh + F1, (float4*)bufB);
    k_gemm3<<<(NN + 127) / 128, 256, 0, stream>>>(bufB, W3, bufA);
    k_agg<6><<<(NN * 6 + 255) / 256, 256, 0, stream>>>(
        (const float4*)bufA, csr, rowstart, dis, bnsc + F1 + F2, bnsh + F1 + F2,
        (float4*)bufB);
    k_cls<<<(NN + 255) / 256, 256, 0, stream>>>(bufB, fc1_W, fc1_b, lnc_g, lnc_b, fc2_W,
                                                fc2_b, (float*)d_out);
}

// Round 3
// 297.240 us; speedup vs baseline: 1.2081x; 1.2081x over previous
//
#include <hip/hip_runtime.h>

#define NN 50000
#define NE 800000
#define DIN 256
#define F1 96
#define F2 48
#define F3 24
#define EPSL 1e-5f
#define NB 196  // ceil(NN/256)

using bf16x8 = __attribute__((ext_vector_type(8))) short;
using f32x4 = __attribute__((ext_vector_type(4))) float;

__device__ __forceinline__ unsigned short f2b(float f) {
    unsigned u = __float_as_uint(f);
    unsigned r = (u + 0x7FFF + ((u >> 16) & 1)) >> 16;
    return (unsigned short)r;
}
__device__ __forceinline__ float b2f(unsigned short h) {
    return __uint_as_float((unsigned)h << 16);
}

// ---------------- edge-index access (int32 or int64 storage) ----------------
__device__ __forceinline__ int ld_src(const int* __restrict__ ei, int is64, int e) {
    return is64 ? ei[2 * e] : ei[e];
}
__device__ __forceinline__ int ld_dst(const int* __restrict__ ei, int is64, int e) {
    return is64 ? ei[2 * NE + 2 * e] : ei[NE + e];
}

__global__ void k_detect(const int* __restrict__ ei, int* __restrict__ flag) {
    if (threadIdx.x == 0 && blockIdx.x == 0) {
        int zeros = 0;
        for (int i = 0; i < 64; i++)
            if (ei[2 * i + 1] == 0) zeros++;
        *flag = (zeros >= 60) ? 1 : 0;  // int64: odd int32 words are high halves == 0
    }
}

// ---------------- degree histogram ----------------
__global__ void k_hist(const int* __restrict__ ei, const int* __restrict__ flag,
                       int* __restrict__ cnt) {
    int e = blockIdx.x * blockDim.x + threadIdx.x;
    if (e < NE) {
        int is64 = *flag;
        atomicAdd(&cnt[ld_dst(ei, is64, e)], 1);
    }
}

// ---------------- scan (exclusive prefix over cnt -> rowstart) ----------------
__global__ void k_scan_reduce(const int* __restrict__ cnt, int* __restrict__ bsum) {
    __shared__ int s[256];
    int t = threadIdx.x;
    int i = blockIdx.x * 256 + t;
    s[t] = (i < NN) ? cnt[i] : 0;
    __syncthreads();
    for (int off = 128; off > 0; off >>= 1) {
        if (t < off) s[t] += s[t + off];
        __syncthreads();
    }
    if (t == 0) bsum[blockIdx.x] = s[0];
}

__global__ void k_scan_top(const int* __restrict__ bsum, int* __restrict__ bsumex,
                           int* __restrict__ rowstart) {
    __shared__ int s[256];
    int t = threadIdx.x;
    int v = (t < NB) ? bsum[t] : 0;
    s[t] = v;
    __syncthreads();
    for (int off = 1; off < 256; off <<= 1) {
        int x = (t >= off) ? s[t - off] : 0;
        __syncthreads();
        s[t] += x;
        __syncthreads();
    }
    if (t < NB) bsumex[t] = s[t] - v;
    if (t == NB - 1) rowstart[NN] = s[t];
}

// also produces dis[] (folded former k_dis)
__global__ void k_scan_fin(const int* __restrict__ cnt, const int* __restrict__ bsumex,
                           int* __restrict__ rowstart, float* __restrict__ dis) {
    __shared__ int s[256];
    int t = threadIdx.x;
    int i = blockIdx.x * 256 + t;
    int v = (i < NN) ? cnt[i] : 0;
    s[t] = v;
    __syncthreads();
    for (int off = 1; off < 256; off <<= 1) {
        int x = (t >= off) ? s[t - off] : 0;
        __syncthreads();
        s[t] += x;
        __syncthreads();
    }
    if (i < NN) {
        rowstart[i] = bsumex[blockIdx.x] + s[t] - v;
        dis[i] = rsqrtf((float)v + 1.0f);
    }
}

// ---------------- CSR fill: csr[i] = {src, weight} ----------------
__global__ void k_fill(const int* __restrict__ ei, const int* __restrict__ flag,
                       const float* __restrict__ dis, const int* __restrict__ rowstart,
                       int* __restrict__ cursor, int2* __restrict__ csr) {
    int e = blockIdx.x * blockDim.x + threadIdx.x;
    if (e < NE) {
        int is64 = *flag;
        int d = ld_dst(ei, is64, e);
        int s = ld_src(ei, is64, e);
        int pos = atomicAdd(&cursor[d], 1);
        float w = dis[s] * dis[d];
        csr[rowstart[d] + pos] = make_int2(s, __float_as_int(w));
    }
}

// ---------------- LayerNorm row stats (one wave per row) ----------------
__global__ void k_lnstats(const float* __restrict__ x, float* __restrict__ mu,
                          float* __restrict__ rstd) {
    int wid = (blockIdx.x * blockDim.x + threadIdx.x) >> 6;
    int lane = threadIdx.x & 63;
    if (wid >= NN) return;
    const float4* xr = (const float4*)(x + (size_t)wid * DIN);
    float4 v = xr[lane];
    float s = v.x + v.y + v.z + v.w;
    float q = v.x * v.x + v.y * v.y + v.z * v.z + v.w * v.w;
    for (int off = 32; off > 0; off >>= 1) {
        s += __shfl_xor(s, off);
        q += __shfl_xor(q, off);
    }
    if (lane == 0) {
        float m = s * (1.f / 256.f);
        float var = q * (1.f / 256.f) - m * m;
        mu[wid] = m;
        rstd[wid] = rsqrtf(var + EPSL);
    }
}

// ---------------- BN constants prep (fold conv bias into BN affine) ----------------
__global__ void k_bnprep(const float* __restrict__ b1, const float* __restrict__ g1,
                         const float* __restrict__ bb1, const float* __restrict__ m1,
                         const float* __restrict__ v1, const float* __restrict__ b2,
                         const float* __restrict__ g2, const float* __restrict__ bb2,
                         const float* __restrict__ m2, const float* __restrict__ v2,
                         const float* __restrict__ b3, const float* __restrict__ g3,
                         const float* __restrict__ bb3, const float* __restrict__ m3,
                         const float* __restrict__ v3, float* __restrict__ sc,
                         float* __restrict__ sh) {
    int t = threadIdx.x;
    if (t < F1) {
        float s = g1[t] * rsqrtf(v1[t] + EPSL);
        sc[t] = s;
        sh[t] = bb1[t] - m1[t] * s + b1[t] * s;
    } else if (t < F1 + F2) {
        int f = t - F1;
        float s = g2[f] * rsqrtf(v2[f] + EPSL);
        sc[t] = s;
        sh[t] = bb2[f] - m2[f] * s + b2[f] * s;
    } else if (t < F1 + F2 + F3) {
        int f = t - F1 - F2;
        float s = g3[f] * rsqrtf(v3[f] + EPSL);
        sc[t] = s;
        sh[t] = bb3[f] - m3[f] * s + b3[f] * s;
    }
}

// ---------------- W1 -> hi/lo bf16 fragments in MFMA order ----------------
// layout: gid = (w*8 + s)*64 + lane ; elem j: k = s*32 + (lane>>4)*8 + j,
//         col = w*16 + (lane&15)
__global__ void k_prepW(const float* __restrict__ W1, ushort* __restrict__ Wh,
                        ushort* __restrict__ Wl) {
    int gid = blockIdx.x * 256 + threadIdx.x;
    if (gid >= 3072) return;
    int l = gid & 63;
    int sw = gid >> 6;
    int s = sw & 7;
    int w = sw >> 3;
    int col = w * 16 + (l & 15);
    int kbase = s * 32 + (l >> 4) * 8;
    ushort hi[8], lo[8];
#pragma unroll
    for (int j = 0; j < 8; j++) {
        float v = W1[(size_t)(kbase + j) * F1 + col];
        ushort h = f2b(v);
        hi[j] = h;
        lo[j] = f2b(v - b2f(h));
    }
    *(uint4*)&Wh[(size_t)gid * 8] = *(uint4*)hi;
    *(uint4*)&Wl[(size_t)gid * 8] = *(uint4*)lo;
}

// ---------------- GEMM1 via split-bf16 MFMA: LN(x)@W1, M=NN K=256 N=96 ------
// block: 384 thr (6 waves), BM=32 rows. wave w owns n-tile w (cols 16w..16w+15),
// holds its B hi/lo fragments in registers for all K.
__global__ __launch_bounds__(384) void k_gemm1m(
    const float* __restrict__ x, const float* __restrict__ mu,
    const float* __restrict__ rstd, const float* __restrict__ ln_g,
    const float* __restrict__ ln_b, const ushort* __restrict__ Wh,
    const ushort* __restrict__ Wl, float* __restrict__ out) {
    __shared__ ushort Ah[1024 * 8];  // 16KB, [rg][s][lane][8] (xor-swizzled)
    __shared__ ushort Al[1024 * 8];  // 16KB
    int tid = threadIdx.x;
    int l = tid & 63;
    int w = tid >> 6;  // wave id = n-tile
    int brow = blockIdx.x * 32;

    // B fragments: 16 x b128 loads, coalesced (pre-swizzled layout)
    bf16x8 Bh[8], Bl[8];
#pragma unroll
    for (int s = 0; s < 8; s++) {
        int gid = (w * 8 + s) * 64 + l;
        Bh[s] = *(const bf16x8*)&Wh[(size_t)gid * 8];
        Bl[s] = *(const bf16x8*)&Wl[(size_t)gid * 8];
    }

    // stage LN(x) as hi/lo bf16 fragments
    for (int t = tid; t < 1024; t += 384) {
        int r = t >> 5;   // 0..31 local row
        int c = t & 31;   // k-slot of 8
        int row = brow + r;
        ushort hi[8], lo[8];
        if (row < NN) {
            float m = mu[row], rs = rstd[row];
            const float4* xp = (const float4*)(x + (size_t)row * DIN + c * 8);
            const float4* gp = (const float4*)(ln_g + c * 8);
            const float4* bp = (const float4*)(ln_b + c * 8);
            float4 v0 = xp[0], v1 = xp[1];
            float4 g0 = gp[0], g1 = gp[1];
            float4 b0 = bp[0], b1 = bp[1];
            float vals[8];
            vals[0] = (v0.x - m) * rs * g0.x + b0.x;
            vals[1] = (v0.y - m) * rs * g0.y + b0.y;
            vals[2] = (v0.z - m) * rs * g0.z + b0.z;
            vals[3] = (v0.w - m) * rs * g0.w + b0.w;
            vals[4] = (v1.x - m) * rs * g1.x + b1.x;
            vals[5] = (v1.y - m) * rs * g1.y + b1.y;
            vals[6] = (v1.z - m) * rs * g1.z + b1.z;
            vals[7] = (v1.w - m) * rs * g1.w + b1.w;
#pragma unroll
            for (int j = 0; j < 8; j++) {
                ushort h = f2b(vals[j]);
                hi[j] = h;
                lo[j] = f2b(vals[j] - b2f(h));
            }
        } else {
#pragma unroll
            for (int j = 0; j < 8; j++) {
                hi[j] = 0;
                lo[j] = 0;
            }
        }
        int s = c >> 2, lh = c & 3, rg = r >> 4;
        int slot = (rg * 8 + s) * 64 + lh * 16 + (r & 15);
        int byte_off = (slot * 16) ^ ((c & 7) << 4);
        *(uint4*)((char*)Ah + byte_off) = *(uint4*)hi;
        *(uint4*)((char*)Al + byte_off) = *(uint4*)lo;
    }
    __syncthreads();

    f32x4 acc0 = {0.f, 0.f, 0.f, 0.f}, acc1 = {0.f, 0.f, 0.f, 0.f};
#pragma unroll
    for (int s = 0; s < 8; s++) {
        int key = ((s * 4 + (l >> 4)) & 7) << 4;
        int b0 = (((0 * 8 + s) * 64 + l) * 16) ^ key;
        int b1 = (((1 * 8 + s) * 64 + l) * 16) ^ key;
        bf16x8 ah0 = *(const bf16x8*)((const char*)Ah + b0);
        bf16x8 al0 = *(const bf16x8*)((const char*)Al + b0);
        bf16x8 ah1 = *(const bf16x8*)((const char*)Ah + b1);
        bf16x8 al1 = *(const bf16x8*)((const char*)Al + b1);
        acc0 = __builtin_amdgcn_mfma_f32_16x16x32_bf16(al0, Bh[s], acc0, 0, 0, 0);
        acc0 = __builtin_amdgcn_mfma_f32_16x16x32_bf16(ah0, Bl[s], acc0, 0, 0, 0);
        acc0 = __builtin_amdgcn_mfma_f32_16x16x32_bf16(ah0, Bh[s], acc0, 0, 0, 0);
        acc1 = __builtin_amdgcn_mfma_f32_16x16x32_bf16(al1, Bh[s], acc1, 0, 0, 0);
        acc1 = __builtin_amdgcn_mfma_f32_16x16x32_bf16(ah1, Bl[s], acc1, 0, 0, 0);
        acc1 = __builtin_amdgcn_mfma_f32_16x16x32_bf16(ah1, Bh[s], acc1, 0, 0, 0);
    }

    // C/D: col = lane&15, row = (lane>>4)*4 + reg
    int colg = w * 16 + (l & 15);
    int rbase = (l >> 4) * 4;
#pragma unroll
    for (int i = 0; i < 4; i++) {
        int row0 = brow + rbase + i;
        if (row0 < NN) out[(size_t)row0 * F1 + colg] = acc0[i];
        int row1 = brow + 16 + rbase + i;
        if (row1 < NN) out[(size_t)row1 * F1 + colg] = acc1[i];
    }
}

// ---------------- GEMM2: h[NN,96] @ W2[96,48]  (BM=64, LDS < 64KB) ----------------
__global__ __launch_bounds__(256) void k_gemm2(const float* __restrict__ A,
                                               const float* __restrict__ W,
                                               float* __restrict__ out) {
    __shared__ float At[F1][68];  // [k][row], 96 x 68
    __shared__ float Ws[F1][F2];
    int tid = threadIdx.x;
    int brow = blockIdx.x * 64;
#pragma unroll
    for (int i = 0; i < 24; i++) {
        int idx = tid + i * 256;  // < 6144 = 96*64
        int r = idx / F1;         // 0..63
        int kk = idx % F1;
        int row = brow + r;
        At[kk][r] = (row < NN) ? A[(size_t)row * F1 + kk] : 0.f;
    }
#pragma unroll
    for (int i = 0; i < 18; i++) {
        int idx = tid + i * 256;
        Ws[idx / F2][idx % F2] = W[idx];
    }
    __syncthreads();
    int rg = tid >> 4;  // 0..15 -> rows rg*4
    int cg = tid & 15;  // 0..15 -> cols cg*3
    float acc[4][3] = {};
#pragma unroll 4
    for (int k = 0; k < F1; k++) {
        float4 a = *(const float4*)&At[k][rg * 4];
        float b[3];
        b[0] = Ws[k][cg * 3];
        b[1] = Ws[k][cg * 3 + 1];
        b[2] = Ws[k][cg * 3 + 2];
#pragma unroll
        for (int j = 0; j < 3; j++) {
            acc[0][j] += a.x * b[j];
            acc[1][j] += a.y * b[j];
            acc[2][j] += a.z * b[j];
            acc[3][j] += a.w * b[j];
        }
    }
#pragma unroll
    for (int i = 0; i < 4; i++) {
        int row = brow + rg * 4 + i;
        if (row < NN) {
            float* o = out + (size_t)row * F2 + cg * 3;
#pragma unroll
            for (int j = 0; j < 3; j++) o[j] = acc[i][j];
        }
    }
}

// ---------------- GEMM3: h[NN,48] @ W3[48,24] ----------------
__global__ __launch_bounds__(256) void k_gemm3(const float* __restrict__ A,
                                               const float* __restrict__ W,
                                               float* __restrict__ out) {
    __shared__ float At[F2][132];  // 48 x 132 (BM=128)
    __shared__ float Ws[F2][F3];
    int tid = threadIdx.x;
    int brow = blockIdx.x * 128;
#pragma unroll
    for (int i = 0; i < 24; i++) {
        int idx = tid + i * 256;  // < 6144 = 48*128
        int r = idx / F2;
        int kk = idx % F2;
        int row = brow + r;
        At[kk][r] = (row < NN) ? A[(size_t)row * F2 + kk] : 0.f;
    }
#pragma unroll
    for (int i = 0; i < 5; i++) {
        int idx = tid + i * 256;
        if (idx < F2 * F3) Ws[idx / F3][idx % F3] = W[idx];
    }
    __syncthreads();
    int rg = tid >> 3;  // rows rg*4 (0..31)
    int cg = tid & 7;   // cols cg*3 (0..7)
    float acc[4][3] = {};
#pragma unroll 4
    for (int k = 0; k < F2; k++) {
        float4 a = *(const float4*)&At[k][rg * 4];
        float b[3];
        b[0] = Ws[k][cg * 3];
        b[1] = Ws[k][cg * 3 + 1];
        b[2] = Ws[k][cg * 3 + 2];
#pragma unroll
        for (int j = 0; j < 3; j++) {
            acc[0][j] += a.x * b[j];
            acc[1][j] += a.y * b[j];
            acc[2][j] += a.z * b[j];
            acc[3][j] += a.w * b[j];
        }
    }
#pragma unroll
    for (int i = 0; i < 4; i++) {
        int row = brow + rg * 4 + i;
        if (row < NN) {
            float* o = out + (size_t)row * F3 + cg * 3;
#pragma unroll
            for (int j = 0; j < 3; j++) o[j] = acc[i][j];
        }
    }
}

// ---------------- CSR gather aggregation + self loop + BN + ReLU ----------------
template <int F4>
__global__ __launch_bounds__(256) void k_agg(const float4* __restrict__ hin,
                                             const int2* __restrict__ csr,
                                             const int* __restrict__ rowstart,
                                             const float* __restrict__ dis,
                                             const float* __restrict__ bnsc,
                                             const float* __restrict__ bnsh,
                                             float4* __restrict__ hout) {
    int t = blockIdx.x * blockDim.x + threadIdx.x;
    if (t >= NN * F4) return;
    int n = t / F4;
    int q = t - n * F4;
    int e0 = rowstart[n], e1 = rowstart[n + 1];
    float4 acc = make_float4(0.f, 0.f, 0.f, 0.f);
    for (int e = e0; e < e1; e++) {
        int2 p = csr[e];
        float w = __int_as_float(p.y);
        float4 hv = hin[(size_t)p.x * F4 + q];
        acc.x += hv.x * w;
        acc.y += hv.y * w;
        acc.z += hv.z * w;
        acc.w += hv.w * w;
    }
    float d = dis[n];
    float d2 = d * d;
    float4 hs = hin[(size_t)n * F4 + q];
    acc.x += hs.x * d2;
    acc.y += hs.y * d2;
    acc.z += hs.z * d2;
    acc.w += hs.w * d2;
    const float4 sc = *(const float4*)&bnsc[q * 4];
    const float4 sh = *(const float4*)&bnsh[q * 4];
    float4 o;
    o.x = fmaxf(acc.x * sc.x + sh.x, 0.f);
    o.y = fmaxf(acc.y * sc.y + sh.y, 0.f);
    o.z = fmaxf(acc.z * sc.z + sh.z, 0.f);
    o.w = fmaxf(acc.w * sc.w + sh.w, 0.f);
    hout[t] = o;
}

// ---------------- classifier: fc1 + LN + relu + fc2 ----------------
__global__ __launch_bounds__(256) void k_cls(const float* __restrict__ h,
                                             const float* __restrict__ fc1W,
                                             const float* __restrict__ fc1b,
                                             const float* __restrict__ lng,
                                             const float* __restrict__ lnb,
                                             const float* __restrict__ fc2W,
                                             const float* __restrict__ fc2b,
                                             float* __restrict__ out) {
    __shared__ float sW1[24 * 12], sW2[12 * 8], sb1[12], sg[12], sb[12], sb2[8];
    int tid = threadIdx.x;
    for (int i = tid; i < 288; i += 256) sW1[i] = fc1W[i];
    if (tid < 96) sW2[tid] = fc2W[tid];
    if (tid < 12) {
        sb1[tid] = fc1b[tid];
        sg[tid] = lng[tid];
        sb[tid] = lnb[tid];
    }
    if (tid < 8) sb2[tid] = fc2b[tid];
    __syncthreads();
    int n = blockIdx.x * blockDim.x + tid;
    if (n >= NN) return;
    float hv[24];
    const float4* hp = (const float4*)(h + (size_t)n * 24);
#pragma unroll
    for (int i = 0; i < 6; i++) {
        float4 v = hp[i];
        hv[i * 4] = v.x;
        hv[i * 4 + 1] = v.y;
        hv[i * 4 + 2] = v.z;
        hv[i * 4 + 3] = v.w;
    }
    float z[12];
#pragma unroll
    for (int j = 0; j < 12; j++) {
        float a = sb1[j];
#pragma unroll
        for (int k = 0; k < 24; k++) a += hv[k] * sW1[k * 12 + j];
        z[j] = a;
    }
    float s = 0.f, q = 0.f;
#pragma unroll
    for (int j = 0; j < 12; j++) {
        s += z[j];
        q += z[j] * z[j];
    }
    float m = s * (1.f / 12.f);
    float var = q * (1.f / 12.f) - m * m;
    float rs = rsqrtf(var + EPSL);
#pragma unroll
    for (int j = 0; j < 12; j++) z[j] = fmaxf((z[j] - m) * rs * sg[j] + sb[j], 0.f);
    float o[8];
#pragma unroll
    for (int c = 0; c < 8; c++) {
        float a = sb2[c];
#pragma unroll
        for (int j = 0; j < 12; j++) a += z[j] * sW2[j * 8 + c];
        o[c] = a;
    }
    float4* op = (float4*)(out + (size_t)n * 8);
    op[0] = make_float4(o[0], o[1], o[2], o[3]);
    op[1] = make_float4(o[4], o[5], o[6], o[7]);
}

// ---------------- launch ----------------
extern "C" void kernel_launch(void* const* d_in, const int* in_sizes, int n_in,
                              void* d_out, int out_size, void* d_ws, size_t ws_size,
                              hipStream_t stream) {
    const float* x = (const float*)d_in[0];
    const int* ei = (const int*)d_in[1];
    const float* ln_g = (const float*)d_in[2];
    const float* ln_b = (const float*)d_in[3];
    const float* W1 = (const float*)d_in[4];
    const float* b1 = (const float*)d_in[5];
    const float* bn1_g = (const float*)d_in[6];
    const float* bn1_b = (const float*)d_in[7];
    const float* bn1_m = (const float*)d_in[8];
    const float* bn1_v = (const float*)d_in[9];
    const float* W2 = (const float*)d_in[10];
    const float* b2 = (const float*)d_in[11];
    const float* bn2_g = (const float*)d_in[12];
    const float* bn2_b = (const float*)d_in[13];
    const float* bn2_m = (const float*)d_in[14];
    const float* bn2_v = (const float*)d_in[15];
    const float* W3 = (const float*)d_in[16];
    const float* b3 = (const float*)d_in[17];
    const float* bn3_g = (const float*)d_in[18];
    const float* bn3_b = (const float*)d_in[19];
    const float* bn3_m = (const float*)d_in[20];
    const float* bn3_v = (const float*)d_in[21];
    const float* fc1_W = (const float*)d_in[22];
    const float* fc1_b = (const float*)d_in[23];
    const float* lnc_g = (const float*)d_in[24];
    const float* lnc_b = (const float*)d_in[25];
    const float* fc2_W = (const float*)d_in[26];
    const float* fc2_b = (const float*)d_in[27];

    char* w = (char*)d_ws;
    auto alloc = [&](size_t bytes) {
        char* p = w;
        w += (bytes + 255) & ~(size_t)255;
        return p;
    };
    int* flag = (int*)alloc(4);
    int* cnt = (int*)alloc(NN * 4);
    int* cursor = (int*)alloc(NN * 4);
    int* bsum = (int*)alloc(1024);
    int* bsumex = (int*)alloc(1024);
    int* rowstart = (int*)alloc((NN + 1) * 4);
    float* dis = (float*)alloc(NN * 4);
    float* mu = (float*)alloc(NN * 4);
    float* rstd = (float*)alloc(NN * 4);
    float* bnsc = (float*)alloc(1024);
    float* bnsh = (float*)alloc(1024);
    int2* csr = (int2*)alloc((size_t)NE * 8);
    float* bufA = (float*)alloc((size_t)NN * F1 * 4);
    float* bufB = (float*)alloc((size_t)NN * F1 * 4);
    ushort* Wh = (ushort*)alloc(3072 * 8 * 2);
    ushort* Wl = (ushort*)alloc(3072 * 8 * 2);

    hipMemsetAsync(cnt, 0, NN * 4, stream);
    hipMemsetAsync(cursor, 0, NN * 4, stream);
    k_detect<<<1, 64, 0, stream>>>(ei, flag);
    k_hist<<<(NE + 255) / 256, 256, 0, stream>>>(ei, flag, cnt);
    k_scan_reduce<<<NB, 256, 0, stream>>>(cnt, bsum);
    k_scan_top<<<1, 256, 0, stream>>>(bsum, bsumex, rowstart);
    k_scan_fin<<<NB, 256, 0, stream>>>(cnt, bsumex, rowstart, dis);
    k_fill<<<(NE + 255) / 256, 256, 0, stream>>>(ei, flag, dis, rowstart, cursor, csr);
    k_lnstats<<<(NN * 64) / 256, 256, 0, stream>>>(x, mu, rstd);
    k_bnprep<<<1, 256, 0, stream>>>(b1, bn1_g, bn1_b, bn1_m, bn1_v, b2, bn2_g, bn2_b,
                                    bn2_m, bn2_v, b3, bn3_g, bn3_b, bn3_m, bn3_v, bnsc,
                                    bnsh);
    k_prepW<<<12, 256, 0, stream>>>(W1, Wh, Wl);
    k_gemm1m<<<(NN + 31) / 32, 384, 0, stream>>>(x, mu, rstd, ln_g, ln_b, Wh, Wl, bufA);
    k_agg<24><<<(NN * 24 + 255) / 256, 256, 0, stream>>>(
        (const float4*)bufA, csr, rowstart, dis, bnsc, bnsh, (float4*)bufB);
    k_gemm2<<<(NN + 63) / 64, 256, 0, stream>>>(bufB, W2, bufA);
    k_agg<12><<<(NN * 12 + 255) / 256, 256, 0, stream>>>(
        (const float4*)bufA, csr, rowstart, dis, bnsc + F1, bnsh + F1, (float4*)bufB);
    k_gemm3<<<(NN + 127) / 128, 256, 0, stream>>>(bufB, W3, bufA);
    k_agg<6><<<(NN * 6 + 255) / 256, 256, 0, stream>>>(
        (const float4*)bufA, csr, rowstart, dis, bnsc + F1 + F2, bnsh + F1 + F2,
        (float4*)bufB);
    k_cls<<<(NN + 255) / 256, 256, 0, stream>>>(bufB, fc1_W, fc1_b, lnc_g, lnc_b, fc2_W,
                                                fc2_b, (float*)d_out);
}

// Round 4
// 245.342 us; speedup vs baseline: 1.4636x; 1.2115x over previous
//
#include <hip/hip_runtime.h>

#define NN 50000
#define NE 800000
#define DIN 256
#define F1 96
#define F2 48
#define F3 24
#define EPSL 1e-5f
#define NB 196  // ceil(NN/256)

using bf16x8 = __attribute__((ext_vector_type(8))) short;
using f32x4 = __attribute__((ext_vector_type(4))) float;

__device__ __forceinline__ unsigned short f2b(float f) {
    unsigned u = __float_as_uint(f);
    unsigned r = (u + 0x7FFF + ((u >> 16) & 1)) >> 16;
    return (unsigned short)r;
}
__device__ __forceinline__ float b2f(unsigned short h) {
    return __uint_as_float((unsigned)h << 16);
}
__device__ __forceinline__ float4 unpk(uint2 u) {
    float4 r;
    r.x = __uint_as_float(u.x << 16);
    r.y = __uint_as_float(u.x & 0xFFFF0000u);
    r.z = __uint_as_float(u.y << 16);
    r.w = __uint_as_float(u.y & 0xFFFF0000u);
    return r;
}

// ---------------- edge-index access (int32 or int64 storage) ----------------
__device__ __forceinline__ int ld_src(const int* __restrict__ ei, int is64, int e) {
    return is64 ? ei[2 * e] : ei[e];
}
__device__ __forceinline__ int ld_dst(const int* __restrict__ ei, int is64, int e) {
    return is64 ? ei[2 * NE + 2 * e] : ei[NE + e];
}

__global__ void k_detect(const int* __restrict__ ei, int* __restrict__ flag) {
    if (threadIdx.x == 0 && blockIdx.x == 0) {
        int zeros = 0;
        for (int i = 0; i < 64; i++)
            if (ei[2 * i + 1] == 0) zeros++;
        *flag = (zeros >= 60) ? 1 : 0;  // int64: odd int32 words are high halves == 0
    }
}

// ---------------- degree histogram ----------------
__global__ void k_hist(const int* __restrict__ ei, const int* __restrict__ flag,
                       int* __restrict__ cnt) {
    int e = blockIdx.x * blockDim.x + threadIdx.x;
    if (e < NE) {
        int is64 = *flag;
        atomicAdd(&cnt[ld_dst(ei, is64, e)], 1);
    }
}

// ---------------- scan (exclusive prefix over cnt -> rowstart) ----------------
__global__ void k_scan_reduce(const int* __restrict__ cnt, int* __restrict__ bsum) {
    __shared__ int s[256];
    int t = threadIdx.x;
    int i = blockIdx.x * 256 + t;
    s[t] = (i < NN) ? cnt[i] : 0;
    __syncthreads();
    for (int off = 128; off > 0; off >>= 1) {
        if (t < off) s[t] += s[t + off];
        __syncthreads();
    }
    if (t == 0) bsum[blockIdx.x] = s[0];
}

__global__ void k_scan_top(const int* __restrict__ bsum, int* __restrict__ bsumex,
                           int* __restrict__ rowstart) {
    __shared__ int s[256];
    int t = threadIdx.x;
    int v = (t < NB) ? bsum[t] : 0;
    s[t] = v;
    __syncthreads();
    for (int off = 1; off < 256; off <<= 1) {
        int x = (t >= off) ? s[t - off] : 0;
        __syncthreads();
        s[t] += x;
        __syncthreads();
    }
    if (t < NB) bsumex[t] = s[t] - v;
    if (t == NB - 1) rowstart[NN] = s[t];
}

// also produces dis[] (folded former k_dis)
__global__ void k_scan_fin(const int* __restrict__ cnt, const int* __restrict__ bsumex,
                           int* __restrict__ rowstart, float* __restrict__ dis) {
    __shared__ int s[256];
    int t = threadIdx.x;
    int i = blockIdx.x * 256 + t;
    int v = (i < NN) ? cnt[i] : 0;
    s[t] = v;
    __syncthreads();
    for (int off = 1; off < 256; off <<= 1) {
        int x = (t >= off) ? s[t - off] : 0;
        __syncthreads();
        s[t] += x;
        __syncthreads();
    }
    if (i < NN) {
        rowstart[i] = bsumex[blockIdx.x] + s[t] - v;
        dis[i] = rsqrtf((float)v + 1.0f);
    }
}

// ---------------- CSR fill: csr[i] = {src, weight} ----------------
__global__ void k_fill(const int* __restrict__ ei, const int* __restrict__ flag,
                       const float* __restrict__ dis, const int* __restrict__ rowstart,
                       int* __restrict__ cursor, int2* __restrict__ csr) {
    int e = blockIdx.x * blockDim.x + threadIdx.x;
    if (e < NE) {
        int is64 = *flag;
        int d = ld_dst(ei, is64, e);
        int s = ld_src(ei, is64, e);
        int pos = atomicAdd(&cursor[d], 1);
        float w = dis[s] * dis[d];
        csr[rowstart[d] + pos] = make_int2(s, __float_as_int(w));
    }
}

// ---------------- LayerNorm row stats (one wave per row) ----------------
__global__ void k_lnstats(const float* __restrict__ x, float* __restrict__ mu,
                          float* __restrict__ rstd) {
    int wid = (blockIdx.x * blockDim.x + threadIdx.x) >> 6;
    int lane = threadIdx.x & 63;
    if (wid >= NN) return;
    const float4* xr = (const float4*)(x + (size_t)wid * DIN);
    float4 v = xr[lane];
    float s = v.x + v.y + v.z + v.w;
    float q = v.x * v.x + v.y * v.y + v.z * v.z + v.w * v.w;
    for (int off = 32; off > 0; off >>= 1) {
        s += __shfl_xor(s, off);
        q += __shfl_xor(q, off);
    }
    if (lane == 0) {
        float m = s * (1.f / 256.f);
        float var = q * (1.f / 256.f) - m * m;
        mu[wid] = m;
        rstd[wid] = rsqrtf(var + EPSL);
    }
}

// ---------------- BN constants prep (fold conv bias into BN affine) ----------------
__global__ void k_bnprep(const float* __restrict__ b1, const float* __restrict__ g1,
                         const float* __restrict__ bb1, const float* __restrict__ m1,
                         const float* __restrict__ v1, const float* __restrict__ b2,
                         const float* __restrict__ g2, const float* __restrict__ bb2,
                         const float* __restrict__ m2, const float* __restrict__ v2,
                         const float* __restrict__ b3, const float* __restrict__ g3,
                         const float* __restrict__ bb3, const float* __restrict__ m3,
                         const float* __restrict__ v3, float* __restrict__ sc,
                         float* __restrict__ sh) {
    int t = threadIdx.x;
    if (t < F1) {
        float s = g1[t] * rsqrtf(v1[t] + EPSL);
        sc[t] = s;
        sh[t] = bb1[t] - m1[t] * s + b1[t] * s;
    } else if (t < F1 + F2) {
        int f = t - F1;
        float s = g2[f] * rsqrtf(v2[f] + EPSL);
        sc[t] = s;
        sh[t] = bb2[f] - m2[f] * s + b2[f] * s;
    } else if (t < F1 + F2 + F3) {
        int f = t - F1 - F2;
        float s = g3[f] * rsqrtf(v3[f] + EPSL);
        sc[t] = s;
        sh[t] = bb3[f] - m3[f] * s + b3[f] * s;
    }
}

// ---------------- W1 -> hi/lo bf16 fragments in MFMA order ----------------
__global__ void k_prepW(const float* __restrict__ W1, ushort* __restrict__ Wh,
                        ushort* __restrict__ Wl) {
    int gid = blockIdx.x * 256 + threadIdx.x;
    if (gid >= 3072) return;
    int l = gid & 63;
    int sw = gid >> 6;
    int s = sw & 7;
    int w = sw >> 3;
    int col = w * 16 + (l & 15);
    int kbase = s * 32 + (l >> 4) * 8;
    ushort hi[8], lo[8];
#pragma unroll
    for (int j = 0; j < 8; j++) {
        float v = W1[(size_t)(kbase + j) * F1 + col];
        ushort h = f2b(v);
        hi[j] = h;
        lo[j] = f2b(v - b2f(h));
    }
    *(uint4*)&Wh[(size_t)gid * 8] = *(uint4*)hi;
    *(uint4*)&Wl[(size_t)gid * 8] = *(uint4*)lo;
}

// ---------------- GEMM1 via split-bf16 MFMA: LN(x)@W1 -> bf16 out ----------
__global__ __launch_bounds__(384) void k_gemm1m(
    const float* __restrict__ x, const float* __restrict__ mu,
    const float* __restrict__ rstd, const float* __restrict__ ln_g,
    const float* __restrict__ ln_b, const ushort* __restrict__ Wh,
    const ushort* __restrict__ Wl, ushort* __restrict__ outb) {
    __shared__ ushort Ah[1024 * 8];  // 16KB, xor-swizzled
    __shared__ ushort Al[1024 * 8];  // 16KB
    int tid = threadIdx.x;
    int l = tid & 63;
    int w = tid >> 6;  // wave id = n-tile
    int brow = blockIdx.x * 32;

    bf16x8 Bh[8], Bl[8];
#pragma unroll
    for (int s = 0; s < 8; s++) {
        int gid = (w * 8 + s) * 64 + l;
        Bh[s] = *(const bf16x8*)&Wh[(size_t)gid * 8];
        Bl[s] = *(const bf16x8*)&Wl[(size_t)gid * 8];
    }

    for (int t = tid; t < 1024; t += 384) {
        int r = t >> 5;
        int c = t & 31;
        int row = brow + r;
        ushort hi[8], lo[8];
        if (row < NN) {
            float m = mu[row], rs = rstd[row];
            const float4* xp = (const float4*)(x + (size_t)row * DIN + c * 8);
            const float4* gp = (const float4*)(ln_g + c * 8);
            const float4* bp = (const float4*)(ln_b + c * 8);
            float4 v0 = xp[0], v1 = xp[1];
            float4 g0 = gp[0], g1 = gp[1];
            float4 b0 = bp[0], b1 = bp[1];
            float vals[8];
            vals[0] = (v0.x - m) * rs * g0.x + b0.x;
            vals[1] = (v0.y - m) * rs * g0.y + b0.y;
            vals[2] = (v0.z - m) * rs * g0.z + b0.z;
            vals[3] = (v0.w - m) * rs * g0.w + b0.w;
            vals[4] = (v1.x - m) * rs * g1.x + b1.x;
            vals[5] = (v1.y - m) * rs * g1.y + b1.y;
            vals[6] = (v1.z - m) * rs * g1.z + b1.z;
            vals[7] = (v1.w - m) * rs * g1.w + b1.w;
#pragma unroll
            for (int j = 0; j < 8; j++) {
                ushort h = f2b(vals[j]);
                hi[j] = h;
                lo[j] = f2b(vals[j] - b2f(h));
            }
        } else {
#pragma unroll
            for (int j = 0; j < 8; j++) {
                hi[j] = 0;
                lo[j] = 0;
            }
        }
        int s = c >> 2, lh = c & 3, rg = r >> 4;
        int slot = (rg * 8 + s) * 64 + lh * 16 + (r & 15);
        int byte_off = (slot * 16) ^ ((c & 7) << 4);
        *(uint4*)((char*)Ah + byte_off) = *(uint4*)hi;
        *(uint4*)((char*)Al + byte_off) = *(uint4*)lo;
    }
    __syncthreads();

    f32x4 acc0 = {0.f, 0.f, 0.f, 0.f}, acc1 = {0.f, 0.f, 0.f, 0.f};
#pragma unroll
    for (int s = 0; s < 8; s++) {
        int key = ((s * 4 + (l >> 4)) & 7) << 4;
        int b0 = (((0 * 8 + s) * 64 + l) * 16) ^ key;
        int b1 = (((1 * 8 + s) * 64 + l) * 16) ^ key;
        bf16x8 ah0 = *(const bf16x8*)((const char*)Ah + b0);
        bf16x8 al0 = *(const bf16x8*)((const char*)Al + b0);
        bf16x8 ah1 = *(const bf16x8*)((const char*)Ah + b1);
        bf16x8 al1 = *(const bf16x8*)((const char*)Al + b1);
        acc0 = __builtin_amdgcn_mfma_f32_16x16x32_bf16(al0, Bh[s], acc0, 0, 0, 0);
        acc0 = __builtin_amdgcn_mfma_f32_16x16x32_bf16(ah0, Bl[s], acc0, 0, 0, 0);
        acc0 = __builtin_amdgcn_mfma_f32_16x16x32_bf16(ah0, Bh[s], acc0, 0, 0, 0);
        acc1 = __builtin_amdgcn_mfma_f32_16x16x32_bf16(al1, Bh[s], acc1, 0, 0, 0);
        acc1 = __builtin_amdgcn_mfma_f32_16x16x32_bf16(ah1, Bl[s], acc1, 0, 0, 0);
        acc1 = __builtin_amdgcn_mfma_f32_16x16x32_bf16(ah1, Bh[s], acc1, 0, 0, 0);
    }

    int colg = w * 16 + (l & 15);
    int rbase = (l >> 4) * 4;
#pragma unroll
    for (int i = 0; i < 4; i++) {
        int row0 = brow + rbase + i;
        if (row0 < NN) outb[(size_t)row0 * F1 + colg] = f2b(acc0[i]);
        int row1 = brow + 16 + rbase + i;
        if (row1 < NN) outb[(size_t)row1 * F1 + colg] = f2b(acc1[i]);
    }
}

// ---------------- GEMM2: a1[NN,96] @ W2[96,48] -> bf16 ----------------
__global__ __launch_bounds__(256) void k_gemm2(const float* __restrict__ A,
                                               const float* __restrict__ W,
                                               ushort* __restrict__ outb) {
    __shared__ float At[F1][68];
    __shared__ float Ws[F1][F2];
    int tid = threadIdx.x;
    int brow = blockIdx.x * 64;
#pragma unroll
    for (int i = 0; i < 24; i++) {
        int idx = tid + i * 256;
        int r = idx / F1;
        int kk = idx % F1;
        int row = brow + r;
        At[kk][r] = (row < NN) ? A[(size_t)row * F1 + kk] : 0.f;
    }
#pragma unroll
    for (int i = 0; i < 18; i++) {
        int idx = tid + i * 256;
        Ws[idx / F2][idx % F2] = W[idx];
    }
    __syncthreads();
    int rg = tid >> 4;
    int cg = tid & 15;
    float acc[4][3] = {};
#pragma unroll 4
    for (int k = 0; k < F1; k++) {
        float4 a = *(const float4*)&At[k][rg * 4];
        float b[3];
        b[0] = Ws[k][cg * 3];
        b[1] = Ws[k][cg * 3 + 1];
        b[2] = Ws[k][cg * 3 + 2];
#pragma unroll
        for (int j = 0; j < 3; j++) {
            acc[0][j] += a.x * b[j];
            acc[1][j] += a.y * b[j];
            acc[2][j] += a.z * b[j];
            acc[3][j] += a.w * b[j];
        }
    }
#pragma unroll
    for (int i = 0; i < 4; i++) {
        int row = brow + rg * 4 + i;
        if (row < NN) {
            ushort* o = outb + (size_t)row * F2 + cg * 3;
#pragma unroll
            for (int j = 0; j < 3; j++) o[j] = f2b(acc[i][j]);
        }
    }
}

// ---------------- GEMM3: a2[NN,48] @ W3[48,24] -> bf16 ----------------
__global__ __launch_bounds__(256) void k_gemm3(const float* __restrict__ A,
                                               const float* __restrict__ W,
                                               ushort* __restrict__ outb) {
    __shared__ float At[F2][132];
    __shared__ float Ws[F2][F3];
    int tid = threadIdx.x;
    int brow = blockIdx.x * 128;
#pragma unroll
    for (int i = 0; i < 24; i++) {
        int idx = tid + i * 256;
        int r = idx / F2;
        int kk = idx % F2;
        int row = brow + r;
        At[kk][r] = (row < NN) ? A[(size_t)row * F2 + kk] : 0.f;
    }
#pragma unroll
    for (int i = 0; i < 5; i++) {
        int idx = tid + i * 256;
        if (idx < F2 * F3) Ws[idx / F3][idx % F3] = W[idx];
    }
    __syncthreads();
    int rg = tid >> 3;
    int cg = tid & 7;
    float acc[4][3] = {};
#pragma unroll 4
    for (int k = 0; k < F2; k++) {
        float4 a = *(const float4*)&At[k][rg * 4];
        float b[3];
        b[0] = Ws[k][cg * 3];
        b[1] = Ws[k][cg * 3 + 1];
        b[2] = Ws[k][cg * 3 + 2];
#pragma unroll
        for (int j = 0; j < 3; j++) {
            acc[0][j] += a.x * b[j];
            acc[1][j] += a.y * b[j];
            acc[2][j] += a.z * b[j];
            acc[3][j] += a.w * b[j];
        }
    }
#pragma unroll
    for (int i = 0; i < 4; i++) {
        int row = brow + rg * 4 + i;
        if (row < NN) {
            ushort* o = outb + (size_t)row * F3 + cg * 3;
#pragma unroll
            for (int j = 0; j < 3; j++) o[j] = f2b(acc[i][j]);
        }
    }
}

// ------- CSR gather agg (bf16 src) + self loop + BN + ReLU -> fp32 out ------
template <int F4>
__global__ __launch_bounds__(256) void k_agg(const ushort* __restrict__ hb,
                                             const int2* __restrict__ csr,
                                             const int* __restrict__ rowstart,
                                             const float* __restrict__ dis,
                                             const float* __restrict__ bnsc,
                                             const float* __restrict__ bnsh,
                                             float4* __restrict__ hout) {
    int t = blockIdx.x * blockDim.x + threadIdx.x;
    if (t >= NN * F4) return;
    int n = t / F4;
    int q = t - n * F4;
    const uint2* hrow = (const uint2*)hb;  // F4 uint2-groups of 4 bf16 per row
    int e0 = rowstart[n], e1 = rowstart[n + 1];
    float4 acc = make_float4(0.f, 0.f, 0.f, 0.f);
    int e = e0;
    for (; e + 4 <= e1; e += 4) {
        int2 p0 = csr[e + 0];
        int2 p1 = csr[e + 1];
        int2 p2 = csr[e + 2];
        int2 p3 = csr[e + 3];
        uint2 u0 = hrow[(size_t)p0.x * F4 + q];
        uint2 u1 = hrow[(size_t)p1.x * F4 + q];
        uint2 u2 = hrow[(size_t)p2.x * F4 + q];
        uint2 u3 = hrow[(size_t)p3.x * F4 + q];
        float w0 = __int_as_float(p0.y);
        float w1 = __int_as_float(p1.y);
        float w2 = __int_as_float(p2.y);
        float w3 = __int_as_float(p3.y);
        float4 h0 = unpk(u0), h1 = unpk(u1), h2 = unpk(u2), h3 = unpk(u3);
        acc.x += h0.x * w0 + h1.x * w1 + h2.x * w2 + h3.x * w3;
        acc.y += h0.y * w0 + h1.y * w1 + h2.y * w2 + h3.y * w3;
        acc.z += h0.z * w0 + h1.z * w1 + h2.z * w2 + h3.z * w3;
        acc.w += h0.w * w0 + h1.w * w1 + h2.w * w2 + h3.w * w3;
    }
    for (; e < e1; e++) {
        int2 p = csr[e];
        float w = __int_as_float(p.y);
        float4 hv = unpk(hrow[(size_t)p.x * F4 + q]);
        acc.x += hv.x * w;
        acc.y += hv.y * w;
        acc.z += hv.z * w;
        acc.w += hv.w * w;
    }
    float d = dis[n];
    float d2 = d * d;
    float4 hs = unpk(hrow[(size_t)n * F4 + q]);
    acc.x += hs.x * d2;
    acc.y += hs.y * d2;
    acc.z += hs.z * d2;
    acc.w += hs.w * d2;
    const float4 sc = *(const float4*)&bnsc[q * 4];
    const float4 sh = *(const float4*)&bnsh[q * 4];
    float4 o;
    o.x = fmaxf(acc.x * sc.x + sh.x, 0.f);
    o.y = fmaxf(acc.y * sc.y + sh.y, 0.f);
    o.z = fmaxf(acc.z * sc.z + sh.z, 0.f);
    o.w = fmaxf(acc.w * sc.w + sh.w, 0.f);
    hout[t] = o;
}

// ---------------- classifier: fc1 + LN + relu + fc2 ----------------
__global__ __launch_bounds__(256) void k_cls(const float* __restrict__ h,
                                             const float* __restrict__ fc1W,
                                             const float* __restrict__ fc1b,
                                             const float* __restrict__ lng,
                                             const float* __restrict__ lnb,
                                             const float* __restrict__ fc2W,
                                             const float* __restrict__ fc2b,
                                             float* __restrict__ out) {
    __shared__ float sW1[24 * 12], sW2[12 * 8], sb1[12], sg[12], sb[12], sb2[8];
    int tid = threadIdx.x;
    for (int i = tid; i < 288; i += 256) sW1[i] = fc1W[i];
    if (tid < 96) sW2[tid] = fc2W[tid];
    if (tid < 12) {
        sb1[tid] = fc1b[tid];
        sg[tid] = lng[tid];
        sb[tid] = lnb[tid];
    }
    if (tid < 8) sb2[tid] = fc2b[tid];
    __syncthreads();
    int n = blockIdx.x * blockDim.x + tid;
    if (n >= NN) return;
    float hv[24];
    const float4* hp = (const float4*)(h + (size_t)n * 24);
#pragma unroll
    for (int i = 0; i < 6; i++) {
        float4 v = hp[i];
        hv[i * 4] = v.x;
        hv[i * 4 + 1] = v.y;
        hv[i * 4 + 2] = v.z;
        hv[i * 4 + 3] = v.w;
    }
    float z[12];
#pragma unroll
    for (int j = 0; j < 12; j++) {
        float a = sb1[j];
#pragma unroll
        for (int k = 0; k < 24; k++) a += hv[k] * sW1[k * 12 + j];
        z[j] = a;
    }
    float s = 0.f, q = 0.f;
#pragma unroll
    for (int j = 0; j < 12; j++) {
        s += z[j];
        q += z[j] * z[j];
    }
    float m = s * (1.f / 12.f);
    float var = q * (1.f / 12.f) - m * m;
    float rs = rsqrtf(var + EPSL);
#pragma unroll
    for (int j = 0; j < 12; j++) z[j] = fmaxf((z[j] - m) * rs * sg[j] + sb[j], 0.f);
    float o[8];
#pragma unroll
    for (int c = 0; c < 8; c++) {
        float a = sb2[c];
#pragma unroll
        for (int j = 0; j < 12; j++) a += z[j] * sW2[j * 8 + c];
        o[c] = a;
    }
    float4* op = (float4*)(out + (size_t)n * 8);
    op[0] = make_float4(o[0], o[1], o[2], o[3]);
    op[1] = make_float4(o[4], o[5], o[6], o[7]);
}

// ---------------- launch ----------------
extern "C" void kernel_launch(void* const* d_in, const int* in_sizes, int n_in,
                              void* d_out, int out_size, void* d_ws, size_t ws_size,
                              hipStream_t stream) {
    const float* x = (const float*)d_in[0];
    const int* ei = (const int*)d_in[1];
    const float* ln_g = (const float*)d_in[2];
    const float* ln_b = (const float*)d_in[3];
    const float* W1 = (const float*)d_in[4];
    const float* b1 = (const float*)d_in[5];
    const float* bn1_g = (const float*)d_in[6];
    const float* bn1_b = (const float*)d_in[7];
    const float* bn1_m = (const float*)d_in[8];
    const float* bn1_v = (const float*)d_in[9];
    const float* W2 = (const float*)d_in[10];
    const float* b2 = (const float*)d_in[11];
    const float* bn2_g = (const float*)d_in[12];
    const float* bn2_b = (const float*)d_in[13];
    const float* bn2_m = (const float*)d_in[14];
    const float* bn2_v = (const float*)d_in[15];
    const float* W3 = (const float*)d_in[16];
    const float* b3 = (const float*)d_in[17];
    const float* bn3_g = (const float*)d_in[18];
    const float* bn3_b = (const float*)d_in[19];
    const float* bn3_m = (const float*)d_in[20];
    const float* bn3_v = (const float*)d_in[21];
    const float* fc1_W = (const float*)d_in[22];
    const float* fc1_b = (const float*)d_in[23];
    const float* lnc_g = (const float*)d_in[24];
    const float* lnc_b = (const float*)d_in[25];
    const float* fc2_W = (const float*)d_in[26];
    const float* fc2_b = (const float*)d_in[27];

    char* w = (char*)d_ws;
    auto alloc = [&](size_t bytes) {
        char* p = w;
        w += (bytes + 255) & ~(size_t)255;
        return p;
    };
    int* flag = (int*)alloc(4);
    int* cnt = (int*)alloc(NN * 4);
    int* cursor = (int*)alloc(NN * 4);
    int* bsum = (int*)alloc(1024);
    int* bsumex = (int*)alloc(1024);
    int* rowstart = (int*)alloc((NN + 1) * 4);
    float* dis = (float*)alloc(NN * 4);
    float* mu = (float*)alloc(NN * 4);
    float* rstd = (float*)alloc(NN * 4);
    float* bnsc = (float*)alloc(1024);
    float* bnsh = (float*)alloc(1024);
    int2* csr = (int2*)alloc((size_t)NE * 8);
    float* bufA = (float*)alloc((size_t)NN * F1 * 4);  // fp32 agg outputs
    ushort* hb = (ushort*)alloc((size_t)NN * F1 * 2);  // bf16 gemm outputs
    ushort* Wh = (ushort*)alloc(3072 * 8 * 2);
    ushort* Wl = (ushort*)alloc(3072 * 8 * 2);

    hipMemsetAsync(cnt, 0, NN * 4, stream);
    hipMemsetAsync(cursor, 0, NN * 4, stream);
    k_detect<<<1, 64, 0, stream>>>(ei, flag);
    k_hist<<<(NE + 255) / 256, 256, 0, stream>>>(ei, flag, cnt);
    k_scan_reduce<<<NB, 256, 0, stream>>>(cnt, bsum);
    k_scan_top<<<1, 256, 0, stream>>>(bsum, bsumex, rowstart);
    k_scan_fin<<<NB, 256, 0, stream>>>(cnt, bsumex, rowstart, dis);
    k_fill<<<(NE + 255) / 256, 256, 0, stream>>>(ei, flag, dis, rowstart, cursor, csr);
    k_lnstats<<<(NN * 64) / 256, 256, 0, stream>>>(x, mu, rstd);
    k_bnprep<<<1, 256, 0, stream>>>(b1, bn1_g, bn1_b, bn1_m, bn1_v, b2, bn2_g, bn2_b,
                                    bn2_m, bn2_v, b3, bn3_g, bn3_b, bn3_m, bn3_v, bnsc,
                                    bnsh);
    k_prepW<<<12, 256, 0, stream>>>(W1, Wh, Wl);
    k_gemm1m<<<(NN + 31) / 32, 384, 0, stream>>>(x, mu, rstd, ln_g, ln_b, Wh, Wl, hb);
    k_agg<24><<<(NN * 24 + 255) / 256, 256, 0, stream>>>(hb, csr, rowstart, dis, bnsc,
                                                         bnsh, (float4*)bufA);
    k_gemm2<<<(NN + 63) / 64, 256, 0, stream>>>(bufA, W2, hb);
    k_agg<12><<<(NN * 12 + 255) / 256, 256, 0, stream>>>(
        hb, csr, rowstart, dis, bnsc + F1, bnsh + F1, (float4*)bufA);
    k_gemm3<<<(NN + 127) / 128, 256, 0, stream>>>(bufA, W3, hb);
    k_agg<6><<<(NN * 6 + 255) / 256, 256, 0, stream>>>(
        hb, csr, rowstart, dis, bnsc + F1 + F2, bnsh + F1 + F2, (float4*)bufA);
    k_cls<<<(NN + 255) / 256, 256, 0, stream>>>(bufA, fc1_W, fc1_b, lnc_g, lnc_b, fc2_W,
                                                fc2_b, (float*)d_out);
}